// Round 1
// baseline (449.710 us; speedup 1.0000x reference)
//
#include <hip/hip_runtime.h>
#include <math.h>

#define T_TOKENS 32768
#define HIDDEN   2048
#define NE       8
#define NT       4          // tokens per wave per iteration
#define BLOCK    512
#define GRID     512

// ws layout (floats): [0..7]=importance sums, [8..15]=load counts, [16]=sum(lse^2)
__global__ __launch_bounds__(BLOCK, 2) void router_main(
    const float* __restrict__ x, const float* __restrict__ W,
    float* __restrict__ out, float* __restrict__ ws)
{
    __shared__ float w_lds[NE * HIDDEN];   // 64 KiB
    __shared__ float s_acc[17];

    if (threadIdx.x < 17) s_acc[threadIdx.x] = 0.0f;

    // Stage W into LDS: 16384 floats, 512 threads * float4 = 2048 floats/iter
#pragma unroll
    for (int j = 0; j < (NE * HIDDEN) / (BLOCK * 4); ++j) {
        const int idx = 4 * (threadIdx.x + BLOCK * j);
        *(float4*)&w_lds[idx] = *(const float4*)&W[idx];
    }
    __syncthreads();

    const int lane   = threadIdx.x & 63;
    const int wave   = blockIdx.x * (BLOCK / 64) + (threadIdx.x >> 6);
    const int nwaves = GRID * (BLOCK / 64);

    for (int g = wave; g < T_TOKENS / NT; g += nwaves) {
        const int t0 = g * NT;

        float acc[NT][NE];
#pragma unroll
        for (int t = 0; t < NT; ++t)
#pragma unroll
            for (int e = 0; e < NE; ++e) acc[t][e] = 0.0f;

#pragma unroll
        for (int c = 0; c < HIDDEN / 256; ++c) {
            const int off = c * 256 + lane * 4;
            float4 xv[NT];
#pragma unroll
            for (int t = 0; t < NT; ++t)
                xv[t] = *(const float4*)(x + (size_t)(t0 + t) * HIDDEN + off);
#pragma unroll
            for (int e = 0; e < NE; ++e) {
                const float4 wv = *(const float4*)&w_lds[e * HIDDEN + off];
#pragma unroll
                for (int t = 0; t < NT; ++t) {
                    acc[t][e] = fmaf(xv[t].x, wv.x,
                                fmaf(xv[t].y, wv.y,
                                fmaf(xv[t].z, wv.z,
                                fmaf(xv[t].w, wv.w, acc[t][e]))));
                }
            }
        }

        // Butterfly reduce each of the NT*NE partial dots across 64 lanes.
#pragma unroll
        for (int t = 0; t < NT; ++t)
#pragma unroll
            for (int e = 0; e < NE; ++e) {
                float v = acc[t][e];
#pragma unroll
                for (int s = 32; s > 0; s >>= 1) v += __shfl_xor(v, s, 64);
                acc[t][e] = v;   // all lanes now hold the total
            }

        // Lanes 0..NT-1 each finish one token.
        if (lane < NT) {
            const int t = t0 + lane;
            float lg[NE];
            float m = -1e30f;
#pragma unroll
            for (int e = 0; e < NE; ++e) { lg[e] = acc[lane][e]; m = fmaxf(m, lg[e]); }
            float p[NE];
            float sum = 0.0f;
#pragma unroll
            for (int e = 0; e < NE; ++e) { p[e] = __expf(lg[e] - m); sum += p[e]; }
            const float inv = 1.0f / sum;
            const float lse = m + __logf(sum);

            // top-2, lower index wins ties (strict >)
            int e1 = 0; float v1 = p[0];
#pragma unroll
            for (int e = 1; e < NE; ++e) if (p[e] > v1) { v1 = p[e]; e1 = e; }
            int e2 = (e1 == 0) ? 1 : 0; float v2 = -1.0f;
#pragma unroll
            for (int e = 0; e < NE; ++e)
                if (e != e1 && p[e] > v2) { v2 = p[e]; e2 = e; }

            float s1 = v1 * inv, s2 = v2 * inv;     // softmax probs of top-2
            const float denom = fmaxf(s1 + s2, 1e-9f);
            out[2 * t]     = (float)e1;
            out[2 * t + 1] = (float)e2;
            out[2 * T_TOKENS + 2 * t]     = s1 / denom;
            out[2 * T_TOKENS + 2 * t + 1] = s2 / denom;

#pragma unroll
            for (int e = 0; e < NE; ++e) atomicAdd(&s_acc[e], p[e] * inv);
            atomicAdd(&s_acc[8 + e1], 1.0f);
            atomicAdd(&s_acc[16], lse * lse);
        }
    }

    __syncthreads();
    if (threadIdx.x < 17) atomicAdd(&ws[threadIdx.x], s_acc[threadIdx.x]);
}

__global__ void router_finalize(const float* __restrict__ ws, float* __restrict__ out)
{
    float impsum = 0.0f, loadsum = 0.0f;
#pragma unroll
    for (int e = 0; e < NE; ++e) { impsum += ws[e]; loadsum += ws[8 + e]; }
    impsum  = fmaxf(impsum, 1e-9f);
    loadsum = fmaxf(loadsum, 1e-9f);
    float lb = 0.0f;
#pragma unroll
    for (int e = 0; e < NE; ++e)
        lb += (ws[e] / impsum) * (ws[8 + e] / loadsum);
    lb *= (float)(NE * NE) * 0.01f;                    // * NUM_EXPERTS^2 * LB_LOSS_COEF
    const float z = ws[16] / (float)T_TOKENS * 0.001f; // mean(lse^2) * Z_LOSS_COEF

    out[4 * T_TOKENS + 0] = z;   // index 131072
    out[4 * T_TOKENS + 1] = lb;  // index 131073
}

extern "C" void kernel_launch(void* const* d_in, const int* in_sizes, int n_in,
                              void* d_out, int out_size, void* d_ws, size_t ws_size,
                              hipStream_t stream)
{
    const float* x = (const float*)d_in[0];
    const float* W = (const float*)d_in[1];
    float* out = (float*)d_out;
    float* ws  = (float*)d_ws;

    hipMemsetAsync(ws, 0, 17 * sizeof(float), stream);
    router_main<<<GRID, BLOCK, 0, stream>>>(x, W, out, ws);
    router_finalize<<<1, 1, 0, stream>>>(ws, out);
}